// Round 12
// baseline (340.350 us; speedup 1.0000x reference)
//
#include <hip/hip_runtime.h>
#include <hip/hip_bf16.h>

#define ED   256   // embed dim
#define NW   8     // num weights
#define NR   5     // num relations
#define BM   128   // rows per block
#define BCOL 128   // cols per block (column half)
// B-panel per relation: BCOL cols x ED k x bf16 = 64 KB, double-buffered

typedef float  f32x4  __attribute__((ext_vector_type(4)));
typedef __bf16 bf16x8 __attribute__((ext_vector_type(8)));
typedef unsigned short u16;

__device__ __forceinline__ u16 f2bf(float f) {
    return __builtin_bit_cast(u16, __float2bfloat16(f));
}

__device__ __forceinline__ bf16x8 pack8(f32x4 a, f32x4 b) {
    union { u16 u[8]; bf16x8 v; } r;
    r.u[0] = f2bf(a[0]); r.u[1] = f2bf(a[1]); r.u[2] = f2bf(a[2]); r.u[3] = f2bf(a[3]);
    r.u[4] = f2bf(b[0]); r.u[5] = f2bf(b[1]); r.u[6] = f2bf(b[2]); r.u[7] = f2bf(b[3]);
    return r.v;
}

// ---------------------------------------------------------------------------
// Prep: S_T[r][j][i] = sum_w ws[w,r] * rel[w, i*ED + j]   (bf16, [col][k])
// ---------------------------------------------------------------------------
__global__ void prep_S(const float* __restrict__ rel,
                       const float* __restrict__ ws,
                       u16* __restrict__ S_T) {
    int idx = blockIdx.x * blockDim.x + threadIdx.x;
    if (idx >= ED * ED) return;
    int i = idx & (ED - 1);
    int j = idx >> 8;
    float acc[NR];
#pragma unroll
    for (int r = 0; r < NR; ++r) acc[r] = 0.f;
#pragma unroll
    for (int w = 0; w < NW; ++w) {
        float rv = rel[(size_t)w * ED * ED + (size_t)i * ED + j];
#pragma unroll
        for (int r = 0; r < NR; ++r) acc[r] += rv * ws[w * NR + r];
    }
#pragma unroll
    for (int r = 0; r < NR; ++r)
        S_T[((size_t)r * ED + j) * ED + i] = f2bf(acc[r]);
}

// ---------------------------------------------------------------------------
// Main: 512 thr = 8 waves, ONE barrier per relation (5 per block, not 40).
// Block (bx,ch): rows bx*128..+128, cols ch*128..+128. Wave (wr,wc):
// 64 rows x 32 cols. A (e1, full K=256) in 128 VGPRs reused over all r;
// e2 in 16 packed VGPRs. Per r: full 64 KB B-panel in LDS (double-buffered,
// staged via global_load_lds w/ XOR swizzle while r-1... r computes), then
// 64 MFMAs/wave uninterrupted, epilogue from regs, vmcnt(0)+s_barrier.
// 1 block/CU, the per-CU MFMA pipe is the designed binding resource.
// ---------------------------------------------------------------------------
__global__ __launch_bounds__(512, 2) void bilinear_kernel(
    const float* __restrict__ e1, const float* __restrict__ e2,
    const u16* __restrict__ S_T, float* __restrict__ out) {

    __shared__ __align__(16) u16 Bbuf[2][BCOL * ED];   // 2 x 64 KB panels
    __shared__ float Red[NR][BM][4];                   // 10 KB

    const int t    = threadIdx.x;
    const int wave = t >> 6;
    const int lane = t & 63;
    const int l15  = lane & 15;
    const int l4   = lane >> 4;
    const int wr   = wave >> 2;    // row group (64 rows), 0..1
    const int wc   = wave & 3;     // col slab (32 cols), 0..3

    // XCD pairing: blocks (bx,0),(bx,1) adjacent on the same XCD L2.
    const int g       = blockIdx.x;
    const int per_xcd = gridDim.x >> 3;
    const int wgid    = (g & 7) * per_xcd + (g >> 3);
    const int ch      = wgid & 1;
    const long b0     = (long)(wgid >> 1) * BM;

    // stage full panel of relation rr -> Bbuf[buf]. LDS layout: [col j][k],
    // col owns 512 B = 32 x 16B chunks; physical chunk = logical ^ (j&7).
    // Source pre-swizzled so LDS dest stays linear (gload_lds constraint).
    auto STAGE = [&](int rr, int buf) {
        const u16* gb = S_T + ((size_t)rr * ED + ch * BCOL) * ED;
#pragma unroll
        for (int q = 0; q < 8; ++q) {
            int idx = q * 512 + t;       // 4096 slots x 16B
            int j   = idx >> 5;          // col 0..127
            int c   = idx & 31;          // physical chunk
            int cl  = c ^ (j & 7);       // logical chunk
            const u16* gp = gb + (size_t)j * ED + cl * 8;
            u16* lp = &Bbuf[buf][(size_t)(q * 512 + wave * 64) * 8];
            __builtin_amdgcn_global_load_lds(
                (const __attribute__((address_space(1))) unsigned int*)gp,
                (__attribute__((address_space(3))) unsigned int*)lp, 16, 0, 0);
        }
    };

    STAGE(0, 0);   // panel r=0

    // ---- A-operand: e1 rows (full K=256) -> 128 VGPRs, reused for all r ----
    bf16x8 av[4][8];
#pragma unroll
    for (int m = 0; m < 4; ++m) {
        const float* rowp = e1 + (b0 + wr * 64 + m * 16 + l15) * ED + l4 * 8;
#pragma unroll
        for (int kb = 0; kb < 8; ++kb) {
            f32x4 a = *(const f32x4*)(rowp + kb * 32);
            f32x4 b = *(const f32x4*)(rowp + kb * 32 + 4);
            av[m][kb] = pack8(a, b);
        }
    }

    // ---- e2 (r-invariant) -> 16 packed VGPRs (2 cols per reg) ----
    unsigned e2p[4][4];
#pragma unroll
    for (int m = 0; m < 4; ++m)
#pragma unroll
        for (int reg = 0; reg < 4; ++reg) {
            const float* erow =
                e2 + (b0 + wr * 64 + m * 16 + l4 * 4 + reg) * ED
                   + ch * BCOL + wc * 32 + l15;
            float a = __builtin_nontemporal_load(erow);
            float b = __builtin_nontemporal_load(erow + 16);
            e2p[m][reg] = (unsigned)f2bf(a) | ((unsigned)f2bf(b) << 16);
        }

    // drain prologue (panel 0 + reg loads), sync
    asm volatile("s_waitcnt vmcnt(0)" ::: "memory");
    __builtin_amdgcn_s_barrier();
    __builtin_amdgcn_sched_barrier(0);

#pragma unroll
    for (int r = 0; r < NR; ++r) {
        // issue next panel's loads; they fly under this r's compute
        if (r + 1 < NR) STAGE(r + 1, (r + 1) & 1);

        f32x4 acc[4][2];
#pragma unroll
        for (int m = 0; m < 4; ++m)
#pragma unroll
            for (int n = 0; n < 2; ++n)
                acc[m][n] = f32x4{0.f, 0.f, 0.f, 0.f};

#pragma unroll
        for (int kb = 0; kb < 8; ++kb) {
            bf16x8 bv[2];
#pragma unroll
            for (int n = 0; n < 2; ++n) {
                int j  = wc * 32 + n * 16 + l15;         // panel col
                int c  = (kb * 4 + l4) ^ (j & 7);        // physical chunk
                bv[n] = *(const bf16x8*)
                    ((const char*)Bbuf[r & 1] + ((size_t)j * 32 + c) * 16);
            }
#pragma unroll
            for (int m = 0; m < 4; ++m)
#pragma unroll
                for (int n = 0; n < 2; ++n)
                    acc[m][n] = __builtin_amdgcn_mfma_f32_16x16x32_bf16(
                        av[m][kb], bv[n], acc[m][n], 0, 0, 0);
        }

        // ---- epilogue r: dot with e2 regs, 16-lane reduce, stash ----
        // C frag: row = wr*64 + m*16 + l4*4 + reg, col = wc*32 + n*16 + l15
#pragma unroll
        for (int m = 0; m < 4; ++m)
#pragma unroll
            for (int reg = 0; reg < 4; ++reg) {
                const int row = wr * 64 + m * 16 + l4 * 4 + reg;
                unsigned u = e2p[m][reg];
                float p = acc[m][0][reg] *
                              __builtin_bit_cast(float, u << 16) +
                          acc[m][1][reg] *
                              __builtin_bit_cast(float, u & 0xffff0000u);
#pragma unroll
                for (int off = 1; off < 16; off <<= 1)
                    p += __shfl_xor(p, off);
                if (l15 == 0) Red[r][row][wc] = p;
            }

        // panel r+1 has been streaming for the whole compute: near-zero wait
        asm volatile("s_waitcnt vmcnt(0)" ::: "memory");
        __builtin_amdgcn_s_barrier();
        __builtin_amdgcn_sched_barrier(0);
    }

    __syncthreads();   // full drain incl. Red ds_writes
    for (int idx = t; idx < BM * NR; idx += 512) {
        int row = idx / NR;
        int r   = idx - row * NR;
        atomicAdd(&out[(b0 + row) * NR + r],
                  Red[r][row][0] + Red[r][row][1] +
                  Red[r][row][2] + Red[r][row][3]);
    }
}

extern "C" void kernel_launch(void* const* d_in, const int* in_sizes, int n_in,
                              void* d_out, int out_size, void* d_ws, size_t ws_size,
                              hipStream_t stream) {
    const float* e1  = (const float*)d_in[0];
    const float* e2  = (const float*)d_in[1];
    const float* rel = (const float*)d_in[2];
    const float* ws  = (const float*)d_in[3];
    float* out = (float*)d_out;
    u16* S_T = (u16*)d_ws;                     // NR*ED*ED bf16 = 640 KB

    prep_S<<<(ED * ED + 255) / 256, 256, 0, stream>>>(rel, ws, S_T);

    hipMemsetAsync(out, 0, (size_t)out_size * sizeof(float), stream);

    int B = in_sizes[0] / ED;                  // 131072
    int grid = (B / BM) * 2;                   // 2048 (row-tiles x col-halves)
    bilinear_kernel<<<grid, 512, 0, stream>>>(e1, e2, S_T, out);
}

// Round 13
// 203.317 us; speedup vs baseline: 1.6740x; 1.6740x over previous
//
#include <hip/hip_runtime.h>
#include <hip/hip_bf16.h>

#define ED   256   // embed dim
#define NW   8     // num weights
#define NR   5     // num relations
#define BM   64    // rows per block
#define BCOL 128   // cols per block (column half)
#define BK   32    // k per stage step -> 8 steps per r, 40 total
#define NSTEP (NR * 8)

typedef float  f32x4  __attribute__((ext_vector_type(4)));
typedef __bf16 bf16x8 __attribute__((ext_vector_type(8)));
typedef unsigned short u16;

__device__ __forceinline__ u16 f2bf(float f) {
    return __builtin_bit_cast(u16, __float2bfloat16(f));
}

__device__ __forceinline__ bf16x8 pack8(f32x4 a, f32x4 b) {
    union { u16 u[8]; bf16x8 v; } r;
    r.u[0] = f2bf(a[0]); r.u[1] = f2bf(a[1]); r.u[2] = f2bf(a[2]); r.u[3] = f2bf(a[3]);
    r.u[4] = f2bf(b[0]); r.u[5] = f2bf(b[1]); r.u[6] = f2bf(b[2]); r.u[7] = f2bf(b[3]);
    return r.v;
}

// ---------------------------------------------------------------------------
// Prep: S_T[r][j][i] = sum_w ws[w,r] * rel[w, i*ED + j]   (bf16, [col][k])
// ---------------------------------------------------------------------------
__global__ void prep_S(const float* __restrict__ rel,
                       const float* __restrict__ ws,
                       u16* __restrict__ S_T) {
    int idx = blockIdx.x * blockDim.x + threadIdx.x;
    if (idx >= ED * ED) return;
    int i = idx & (ED - 1);
    int j = idx >> 8;
    float acc[NR];
#pragma unroll
    for (int r = 0; r < NR; ++r) acc[r] = 0.f;
#pragma unroll
    for (int w = 0; w < NW; ++w) {
        float rv = rel[(size_t)w * ED * ED + (size_t)i * ED + j];
#pragma unroll
        for (int r = 0; r < NR; ++r) acc[r] += rv * ws[w * NR + r];
    }
#pragma unroll
    for (int r = 0; r < NR; ++r)
        S_T[((size_t)r * ED + j) * ED + i] = f2bf(acc[r]);
}

// ---------------------------------------------------------------------------
// Main: 256 thr = 4 waves. Block (bx,ch): rows bx*64..+64, cols ch*128..+128.
// Wave (wr,wc): 32 rows x 64 cols. A (e1, full K=256) in 64 VGPRs reused over
// all r; e2 in 16 packed VGPRs. B (S_T) staged through a 4-slot LDS ring
// (BK=32 -> 8 KB chunks, 32 KB total -> target 4 blocks/CU) via
// global_load_lds + XOR swizzle. Counted vmcnt (4 steady / 2 / 0 tail) + raw
// s_barrier per step; stage chunk s+2 while computing s (ring-4 WAR-safe).
// min-waves=3: do NOT force a 128-reg cap (R6/R9/R10-proposal spill lesson).
// ---------------------------------------------------------------------------
__global__ __launch_bounds__(256, 3) void bilinear_kernel(
    const float* __restrict__ e1, const float* __restrict__ e2,
    const u16* __restrict__ S_T, float* __restrict__ out) {

    __shared__ __align__(16) u16 Bbuf[4][BCOL * BK];   // 4 x 8 KB ring
    __shared__ float Red[NR][BM][2];                   // 2.5 KB

    const int t    = threadIdx.x;
    const int wave = t >> 6;
    const int lane = t & 63;
    const int l15  = lane & 15;
    const int l4   = lane >> 4;
    const int wr   = wave >> 1;    // row group (32 rows)
    const int wc   = wave & 1;     // col slab (64 cols within the 128)

    // XCD pairing: blocks (bx,0),(bx,1) adjacent on the same XCD L2.
    const int g       = blockIdx.x;
    const int per_xcd = gridDim.x >> 3;
    const int wgid    = (g & 7) * per_xcd + (g >> 3);
    const int ch      = wgid & 1;
    const long b0     = (long)(wgid >> 1) * BM;

    // staging: chunk (rr,kb) -> ring slot b. LDS linear, global pre-swizzled.
    // col j owns 64 B (4 x 16B chunks); physical chunk c holds logical
    // c ^ ((j>>1)&3)  (involution; measured 164K conflicts in R6-proposal).
    auto STAGE = [&](int rr, int kb, int b) {
        const u16* gb = S_T + ((size_t)rr * ED + ch * BCOL) * ED + kb * BK;
#pragma unroll
        for (int q = 0; q < 2; ++q) {
            int s2 = q * 256 + t;        // 512 slots x 16B
            int j  = s2 >> 2;            // col 0..127
            int c  = s2 & 3;             // physical 16B chunk within col
            int cl = c ^ ((j >> 1) & 3); // logical chunk (inverse swizzle)
            const u16* gp = gb + (size_t)j * ED + cl * 8;
            u16* lp = &Bbuf[b][(size_t)(q * 256 + wave * 64) * 8]; // wave-uniform
            __builtin_amdgcn_global_load_lds(
                (const __attribute__((address_space(1))) unsigned int*)gp,
                (__attribute__((address_space(3))) unsigned int*)lp, 16, 0, 0);
        }
    };

    STAGE(0, 0, 0);   // chunk 0
    STAGE(0, 1, 1);   // chunk 1

    // ---- A-operand: e1 rows (full K=256) -> 64 VGPRs, reused for all r ----
    bf16x8 av[2][8];
#pragma unroll
    for (int m = 0; m < 2; ++m) {
        const float* rowp = e1 + (b0 + wr * 32 + m * 16 + l15) * ED + l4 * 8;
#pragma unroll
        for (int kb = 0; kb < 8; ++kb) {
            f32x4 a = *(const f32x4*)(rowp + kb * 32);
            f32x4 b = *(const f32x4*)(rowp + kb * 32 + 4);
            av[m][kb] = pack8(a, b);
        }
    }

    // ---- e2 (r-invariant) -> 16 packed VGPRs ----
    unsigned e2p[2][4][2];
#pragma unroll
    for (int m = 0; m < 2; ++m)
#pragma unroll
        for (int reg = 0; reg < 4; ++reg) {
            const float* erow =
                e2 + (b0 + wr * 32 + m * 16 + l4 * 4 + reg) * ED
                   + ch * BCOL + wc * 64 + l15;
#pragma unroll
            for (int h = 0; h < 2; ++h) {
                float a = __builtin_nontemporal_load(erow + (2 * h) * 16);
                float b = __builtin_nontemporal_load(erow + (2 * h + 1) * 16);
                e2p[m][reg][h] = (unsigned)f2bf(a) | ((unsigned)f2bf(b) << 16);
            }
        }

    // clean vmcnt bookkeeping: prologue loads (incl. chunks 0,1) all land here
    asm volatile("s_waitcnt vmcnt(0)" ::: "memory");
    __builtin_amdgcn_s_barrier();

#pragma unroll
    for (int r = 0; r < NR; ++r) {
        f32x4 acc[2][4];
#pragma unroll
        for (int m = 0; m < 2; ++m)
#pragma unroll
            for (int n = 0; n < 4; ++n)
                acc[m][n] = f32x4{0.f, 0.f, 0.f, 0.f};

#pragma unroll
        for (int kb = 0; kb < 8; ++kb) {
            const int s = r * 8 + kb;            // static after unroll

            // stage chunk s+2 into ring slot (s+2)&3 (overwrites chunk s-2,
            // whose reads completed before barrier(s-1))
            if (s + 2 < NSTEP) {
                const int sn = s + 2;
                STAGE(sn >> 3, sn & 7, sn & 3);
            }

            // counted wait: chunk s landed when only s+1,s+2 (2x2 loads) fly
            if (s < NSTEP - 2)
                asm volatile("s_waitcnt vmcnt(4)" ::: "memory");
            else if (s == NSTEP - 2)
                asm volatile("s_waitcnt vmcnt(2)" ::: "memory");
            else
                asm volatile("s_waitcnt vmcnt(0)" ::: "memory");
            __builtin_amdgcn_s_barrier();

            // B fragments from ring slot s&3 (swizzled read)
            bf16x8 bv[4];
#pragma unroll
            for (int n = 0; n < 4; ++n) {
                int j  = wc * 64 + n * 16 + l15;             // local col
                int lb = j * (BK * 2) + l4 * 16;             // logical byte
                int pb = lb ^ (((j >> 1) & 3) << 4);         // physical byte
                bv[n] = *(const bf16x8*)((const char*)Bbuf[s & 3] + pb);
            }
#pragma unroll
            for (int m = 0; m < 2; ++m)
#pragma unroll
                for (int n = 0; n < 4; ++n)
                    acc[m][n] = __builtin_amdgcn_mfma_f32_16x16x32_bf16(
                        av[m][kb], bv[n], acc[m][n], 0, 0, 0);
        }

        // ---- epilogue r: dot with e2 regs, 16-lane reduce, stash ----
        // C frag: row = wr*32 + m*16 + l4*4 + reg, col = wc*64 + n*16 + l15
#pragma unroll
        for (int m = 0; m < 2; ++m)
#pragma unroll
            for (int reg = 0; reg < 4; ++reg) {
                const int row = wr * 32 + m * 16 + l4 * 4 + reg;
                float p = 0.f;
#pragma unroll
                for (int n = 0; n < 4; ++n) {
                    unsigned u = e2p[m][reg][n >> 1];
                    unsigned bits = (n & 1) ? (u & 0xffff0000u) : (u << 16);
                    p += acc[m][n][reg] * __builtin_bit_cast(float, bits);
                }
#pragma unroll
                for (int off = 1; off < 16; off <<= 1)
                    p += __shfl_xor(p, off);
                if (l15 == 0) Red[r][row][wc] = p;
            }
    }

    __syncthreads();
    for (int idx = t; idx < BM * NR; idx += 256) {
        int row = idx / NR;
        int r   = idx - row * NR;
        atomicAdd(&out[(b0 + row) * NR + r], Red[r][row][0] + Red[r][row][1]);
    }
}

extern "C" void kernel_launch(void* const* d_in, const int* in_sizes, int n_in,
                              void* d_out, int out_size, void* d_ws, size_t ws_size,
                              hipStream_t stream) {
    const float* e1  = (const float*)d_in[0];
    const float* e2  = (const float*)d_in[1];
    const float* rel = (const float*)d_in[2];
    const float* ws  = (const float*)d_in[3];
    float* out = (float*)d_out;
    u16* S_T = (u16*)d_ws;                     // NR*ED*ED bf16 = 640 KB

    prep_S<<<(ED * ED + 255) / 256, 256, 0, stream>>>(rel, ws, S_T);

    hipMemsetAsync(out, 0, (size_t)out_size * sizeof(float), stream);

    int B = in_sizes[0] / ED;                  // 131072
    int grid = (B / BM) * 2;                   // 4096 (row-tiles x col-halves)
    bilinear_kernel<<<grid, 256, 0, stream>>>(e1, e2, S_T, out);
}